// Round 17
// baseline (107.362 us; speedup 1.0000x reference)
//
#include <hip/hip_runtime.h>

// HDR+ align, 4-kernel pipeline, round 20 = R19 (best, 102.7us) with K2b
// split once more: K2b1 (S1-only, 1024x256, writes per-S1-tile offsets) +
// K2b2 (S0-only, 4096x128 = one block per S0 tile, 100% occupancy phase).
// All round internals verbatim; offsets transported bitwise through ws.
// Constants: T=16, SR=4, PADD=1, SS=11, SSC=9, WIN=26, SW=0.1, GR=2, batch 4, 512x512.

#define NB 4
#define NPIX (NB * 512 * 512)
#define OFFS_BASE 1212416        // floats: after dL3; S2 offsets (512 fl)
#define OFFS1_BASE (OFFS_BASE + 512)   // S1 offsets (2048 fl)

// Composite 1D tap of (normalized gaussian sigma=1 r=2) followed by avg-pool-2.
constexpr float H6[6] = {
    0.027244342f, 0.149345013f, 0.323410645f,
    0.323410645f, 0.149345013f, 0.027244342f
};

// ---------------------------------------------------------------------------
// K1: pyramid. One block = 8x4 region of L3 (covers 64x32 L0). Grid (8,16,8).
// (Verbatim R17/R19.)
// ---------------------------------------------------------------------------
__global__ void __launch_bounds__(256, 4)
pyramid_kernel(const float* __restrict__ src, const float* __restrict__ dst,
               float* __restrict__ ws) {
    __shared__ float smem[8160];
    float* patch = smem;            // 60 rows, stride 92
    float* tmpH1 = smem + 5520;     // 60 rows, stride 44
    float* l1    = smem;            // 28 rows, stride 44
    float* tmpH2 = smem + 1232;     // 28 rows, stride 20
    float* l2    = smem + 1792;     // 12 rows, stride 20
    float* tmpH3 = smem + 2032;     // 12 rows, stride 8

    float* sL1 = ws;
    float* dL1 = sL1 + 4 * 65536;
    float* sL2 = dL1 + 4 * 65536;
    float* dL2 = sL2 + 4 * 16384;
    float* sL3 = dL2 + 4 * 16384;
    float* dL3 = sL3 + 4 * 4096;

    const int bx = blockIdx.x, by = blockIdx.y, z = blockIdx.z;
    const int t = threadIdx.x;
    const float* in = (z < 4) ? (src + (size_t)z * 262144) : (dst + (size_t)(z - 4) * 262144);
    float* oL1 = ((z < 4) ? sL1 : dL1) + (size_t)(z & 3) * 65536;
    float* oL2 = ((z < 4) ? sL2 : dL2) + (size_t)(z & 3) * 16384;
    float* oL3 = ((z < 4) ? sL3 : dL3) + (size_t)(z & 3) * 4096;

    // P0: 60x92 L0 patch at (by*32-14, bx*64-14), zero OOB (conv zero-pad).
    {
        const int oy = by * 32 - 14, ox = bx * 64 - 14;
        for (int idx = t; idx < 5520; idx += 256) {
            int r = idx / 92, c = idx - r * 92;
            int gy = oy + r, gx = ox + c;
            float v = 0.f;
            if ((unsigned)gy < 512u && (unsigned)gx < 512u) v = in[gy * 512 + gx];
            patch[r * 92 + c] = v;
        }
    }
    __syncthreads();
    // P1: horizontal -> tmpH1[60][44]
    for (int idx = t; idx < 2640; idx += 256) {
        int r = idx / 44, v = idx - r * 44;
        const float* p = &patch[r * 92 + 2 * v];
        float a = 0.f;
        #pragma unroll
        for (int bq = 0; bq < 6; ++bq) a = fmaf(H6[bq], p[bq], a);
        tmpH1[r * 44 + v] = a;
    }
    __syncthreads();
    // P2: vertical -> l1[28][44]; zero if L1 coord OOB (per-level zero-pad).
    {
        const int oy = by * 16 - 6, ox = bx * 32 - 6;
        for (int idx = t; idx < 1232; idx += 256) {
            int u = idx / 44, v = idx - u * 44;
            float a = 0.f;
            int y1 = oy + u, x1 = ox + v;
            if ((unsigned)y1 < 256u && (unsigned)x1 < 256u) {
                #pragma unroll
                for (int bq = 0; bq < 6; ++bq) a = fmaf(H6[bq], tmpH1[(2 * u + bq) * 44 + v], a);
            }
            l1[u * 44 + v] = a;
        }
    }
    __syncthreads();
    // P3: write canonical L1 16x32 + horizontal -> tmpH2[28][20]
    {
        #pragma unroll
        for (int k = 0; k < 2; ++k) {
            int idx = t + k * 256;
            int u = idx >> 5, v = idx & 31;
            oL1[(by * 16 + u) * 256 + bx * 32 + v] = l1[(6 + u) * 44 + 6 + v];
        }
    }
    for (int idx = t; idx < 560; idx += 256) {
        int r = idx / 20, v = idx - r * 20;
        const float* p = &l1[r * 44 + 2 * v];
        float a = 0.f;
        #pragma unroll
        for (int bq = 0; bq < 6; ++bq) a = fmaf(H6[bq], p[bq], a);
        tmpH2[r * 20 + v] = a;
    }
    __syncthreads();
    // P4: vertical -> l2[12][20]; zero if L2 coord OOB.
    {
        const int oy = by * 8 - 2, ox = bx * 16 - 2;
        if (t < 240) {
            int u = t / 20, v = t - u * 20;
            float a = 0.f;
            int y2 = oy + u, x2 = ox + v;
            if ((unsigned)y2 < 128u && (unsigned)x2 < 128u) {
                #pragma unroll
                for (int bq = 0; bq < 6; ++bq) a = fmaf(H6[bq], tmpH2[(2 * u + bq) * 20 + v], a);
            }
            l2[u * 20 + v] = a;
        }
    }
    __syncthreads();
    // P5: write canonical L2 8x16 + horizontal -> tmpH3[12][8]
    if (t < 128) {
        int u = t >> 4, v = t & 15;
        oL2[(by * 8 + u) * 128 + bx * 16 + v] = l2[(2 + u) * 20 + 2 + v];
    } else if (t < 224) {
        int idx = t - 128;
        int r = idx >> 3, v = idx & 7;
        const float* p = &l2[r * 20 + 2 * v];
        float a = 0.f;
        #pragma unroll
        for (int bq = 0; bq < 6; ++bq) a = fmaf(H6[bq], p[bq], a);
        tmpH3[r * 8 + v] = a;
    }
    __syncthreads();
    // P6: vertical -> L3 4x8, write global.
    if (t < 32) {
        int u = t >> 3, v = t & 7;
        float a = 0.f;
        #pragma unroll
        for (int bq = 0; bq < 6; ++bq) a = fmaf(H6[bq], tmpH3[(2 * u + bq) * 8 + v], a);
        oL3[(by * 4 + u) * 64 + bx * 8 + v] = a;
    }
}

// ---------------------------------------------------------------------------
// K2 helpers (verbatim: SSD/argmin bit-identical; st row stride 20 floats).
// ---------------------------------------------------------------------------
__device__ __forceinline__ void inherit_off(int ty, int tx, int H,
                                            float pary, float parx,
                                            float& dyf, float& dxf) {
    float iy = (float)(ty * 16), ix = (float)(tx * 16);
    // _inherit: round(clip(2*par + i, 0, H-16) - i), half-to-even (rintf).
    dyf = rintf(fminf(fmaxf(2.f * pary + iy, 0.f), (float)(H - 16)) - iy);
    dxf = rintf(fminf(fmaxf(2.f * parx + ix, 0.f), (float)(H - 16)) - ix);
}

// Division-free window load: lane owns column c = lt&31 (clamp hoisted),
// rows stride by NL/32.
template<int NL>
__device__ __forceinline__ void load_win(const float* __restrict__ dimg, int H,
                                         int y0, int x0, float* win, int lt) {
    const int c = lt & 31;
    const int r0 = lt >> 5;              // NL=256: 0..7 ; NL=128: 0..3
    constexpr int RSTEP = NL / 32;
    if (c < 26) {
        const int gx = min(max(x0 + c, 0), H - 1);
        #pragma unroll
        for (int k = 0; k < (26 + RSTEP - 1) / RSTEP; ++k) {
            const int rr = r0 + k * RSTEP;
            if (rr < 26) {
                const int gy = min(max(y0 + rr, 0), H - 1);
                win[rr * 28 + c] = dimg[gy * H + gx];
            }
        }
    }
}

// SSD + dist write. FULL: 1 row/lane, 16-lane dy-groups (lt in [0,256)).
// !FULL: 2 rows/lane, 8-lane dy-groups (lt in [0,128)). No barriers inside.
template<bool FULL>
__device__ __forceinline__ void ssd_dist(const float* win, const float* st,
                                         float* dist, int lt) {
    const int dy = FULL ? (lt >> 4) : (lt >> 3);
    if (dy < 11) {
        float acc[11];
        #pragma unroll
        for (int q = 0; q < 11; ++q) acc[q] = 0.f;
        constexpr int ROWS = FULL ? 1 : 2;
        #pragma unroll
        for (int rr = 0; rr < ROWS; ++rr) {
            const int i = FULL ? (lt & 15) : ((lt & 7) * 2 + rr);
            float w[28], s[16];
            const float4* wp = (const float4*)&win[(dy + i) * 28];
            #pragma unroll
            for (int q = 0; q < 7; ++q) ((float4*)w)[q] = wp[q];
            const float4* sp = (const float4*)&st[i * 20];
            #pragma unroll
            for (int q = 0; q < 4; ++q) ((float4*)s)[q] = sp[q];
            #pragma unroll
            for (int dx = 0; dx < 11; ++dx) {
                #pragma unroll
                for (int j = 0; j < 16; ++j) {
                    float d = w[dx + j] - s[j];
                    acc[dx] = fmaf(d, d, acc[dx]);
                }
            }
        }
        constexpr int MMAX = FULL ? 8 : 4;
        #pragma unroll
        for (int m = 1; m <= MMAX; m <<= 1) {
            #pragma unroll
            for (int dx = 0; dx < 11; ++dx) acc[dx] += __shfl_xor(acc[dx], m);
        }
        const bool leader = FULL ? ((lt & 15) == 0) : ((lt & 7) == 0);
        if (leader) {
            float ay = (float)(dy - 5) * (1.f / 11.f);
            #pragma unroll
            for (int dx = 0; dx < 11; ++dx) {
                float ax = (float)(dx - 5) * (1.f / 11.f);
                dist[dy * 11 + dx] = acc[dx] * (1.f / 256.f) + 0.1f * (ay * ay + ax * ax);
            }
        }
    }
}

// Redundant per-lane argmin over central 9x9 + subpixel refine (baseline).
__device__ __forceinline__ void argmin_refine(const float* dist, int lt,
                                              float dyf, float dxf,
                                              float& roy, float& rox, float& rod) {
    const int l = lt & 63;
    float bv; int bk;
    {
        int k = l;                                    // 0..63 < 81 always
        int py = k / 9, px = k - (k / 9) * 9;
        bv = dist[(py + 1) * 11 + (px + 1)]; bk = k;
        k = l + 64;
        if (k < 81) {
            py = k / 9; px = k - (k / 9) * 9;
            float d = dist[(py + 1) * 11 + (px + 1)];
            if (d < bv) { bv = d; bk = k; }           // strict: tie keeps smaller k
        }
    }
    #pragma unroll
    for (int m = 1; m <= 32; m <<= 1) {
        float ov = __shfl_xor(bv, m);
        int   ok = __shfl_xor(bk, m);
        if (ov < bv || (ov == bv && ok < bk)) { bv = ov; bk = ok; }
    }
    {
        int py = bk / 9, px = bk - (bk / 9) * 9;
        float y00 = dist[(py + 0) * 11 + (px + 0)], y01 = dist[(py + 0) * 11 + (px + 1)], y02 = dist[(py + 0) * 11 + (px + 2)];
        float y10 = dist[(py + 1) * 11 + (px + 0)], y11 = dist[(py + 1) * 11 + (px + 1)], y12 = dist[(py + 1) * 11 + (px + 2)];
        float y20 = dist[(py + 2) * 11 + (px + 0)], y21 = dist[(py + 2) * 11 + (px + 1)], y22 = dist[(py + 2) * 11 + (px + 2)];

        float a11 = (y00 - 2.f * y01 + y02 + 2.f * y10 - 4.f * y11 + 2.f * y12 + y20 - 2.f * y21 + y22) * 0.25f;
        a11 = fmaxf(a11, 0.f);
        float a22 = (y00 + 2.f * y01 + y02 - 2.f * y10 - 4.f * y11 - 2.f * y12 + y20 + 2.f * y21 + y22) * 0.25f;
        a22 = fmaxf(a22, 0.f);
        float a12 = (y00 - y02 - y20 + y22) * 0.25f;
        float b1  = (-y00 + y02 - 2.f * y10 + 2.f * y12 - y20 + y22) * 0.125f;
        float b2  = (-y00 - 2.f * y01 - y02 + y20 + 2.f * y21 + y22) * 0.125f;

        float det  = a11 * a22 - a12 * a12;
        float a12z = (det < 0.f) ? 0.f : a12;
        float mu_x = -(a22 * b1 - a12z * b2) / det;   // inf/nan when det==0 -> filtered
        float mu_y = -(a11 * b2 - a12z * b1) / det;
        float mu_len = sqrtf(mu_x * mu_x + mu_y * mu_y);
        float addx = (mu_len < 1.f) ? mu_x : 0.f;     // NaN -> false, matches jnp.where
        float addy = (mu_len < 1.f) ? mu_y : 0.f;

        roy = dyf + (float)(py - 4) + addy;
        rox = dxf + (float)(px - 4) + addx;
        rod = bv;
    }
}

// ---------------------------------------------------------------------------
// K2a: seed. One block per S2 tile (256 blocks, 256 thr). S3 (redundant x4,
// bitwise identical) then S2; writes final S2 offset to ws. (Verbatim R19.)
// ---------------------------------------------------------------------------
__global__ void __launch_bounds__(256, 4)
seed_kernel(const float* __restrict__ ws_ro, float* __restrict__ ws) {
    __shared__ float smem[1496];
    float* win_c  = smem;
    float* dist_c = smem + 728;
    float* stL3   = smem + 856;     // [16][20]
    float* stL2   = smem + 1176;    // [16][20]

    const float* sL2 = ws_ro + 4 * 65536 + 4 * 65536;
    const float* dL2 = sL2 + 4 * 16384;
    const float* sL3 = dL2 + 4 * 16384;
    const float* dL3 = sL3 + 4 * 4096;
    float* offs = ws + OFFS_BASE;

    const int gid = blockIdx.x;
    const int b   = gid >> 6;
    const int ty2 = (gid >> 3) & 7;
    const int tx2 = gid & 7;
    const int t   = threadIdx.x;

    const float* s2 = sL2 + (size_t)b * 16384;  const float* d2 = dL2 + (size_t)b * 16384;
    const float* s3 = sL3 + (size_t)b * 4096;   const float* d3 = dL3 + (size_t)b * 4096;

    // Entry: st loads (stride-20 rows).
    {
        const int it = t & 63, r = it >> 2, q = t & 3;
        if (t < 64) {
            const float4* p = (const float4*)(s3 + (size_t)((ty2 >> 1) * 16 + r) * 64 + (tx2 >> 1) * 16);
            ((float4*)&stL3[r * 20])[q] = p[q];
        } else if (t < 128) {
            const float4* p = (const float4*)(s2 + (size_t)(ty2 * 16 + r) * 128 + tx2 * 16);
            ((float4*)&stL2[r * 20])[q] = p[q];
        }
    }

    float oy, ox, od;
    // S3 (init offset 0)
    load_win<256>(d3, 64, (ty2 >> 1) * 16 - 5, (tx2 >> 1) * 16 - 5, win_c, t);
    __syncthreads();
    ssd_dist<true>(win_c, stL3, dist_c, t);
    __syncthreads();
    argmin_refine(dist_c, t, 0.f, 0.f, oy, ox, od);
    // S2
    {
        float dyf, dxf; inherit_off(ty2, tx2, 128, oy, ox, dyf, dxf);
        load_win<256>(d2, 128, ty2 * 16 + (int)dyf - 5, tx2 * 16 + (int)dxf - 5, win_c, t);
        __syncthreads();
        ssd_dist<true>(win_c, stL2, dist_c, t);
        __syncthreads();
        argmin_refine(dist_c, t, dyf, dxf, oy, ox, od);
    }
    if (t == 0) {
        const int oi = ((b * 8 + ty2) * 8 + tx2) * 2;
        offs[oi]     = oy;
        offs[oi + 1] = ox;
    }
}

// ---------------------------------------------------------------------------
// K2b1: S1-only. One block per S1 tile (1024 blocks, 256 thr). Loads parent
// S2 offset; one verbatim S1 round; writes final S1 offset to ws.
// LDS: win_c 728 | dist_c 128 | stL1 320 = 1176 fl.
// ---------------------------------------------------------------------------
__global__ void __launch_bounds__(256, 4)
s1_kernel(const float* __restrict__ ws_ro, float* __restrict__ ws) {
    __shared__ float smem[1176];
    float* win_c  = smem;
    float* dist_c = smem + 728;
    float* stL1   = smem + 856;     // [16][20]

    const float* sL1 = ws_ro;
    const float* dL1 = sL1 + 4 * 65536;
    const float* offs = ws_ro + OFFS_BASE;
    float* offs1 = ws + OFFS1_BASE;

    const int gid = blockIdx.x;
    const int b   = gid >> 8;
    const int ty1 = (gid >> 4) & 15;
    const int tx1 = gid & 15;
    const int t   = threadIdx.x;

    const float* s1 = sL1 + (size_t)b * 65536;
    const float* d1 = dL1 + (size_t)b * 65536;

    // Parent S2 offset (uniform per block).
    const int oi = ((b * 8 + (ty1 >> 1)) * 8 + (tx1 >> 1)) * 2;
    const float poy = offs[oi], pox = offs[oi + 1];

    // Entry: stL1 load (stride-20 rows).
    if (t < 64) {
        const int r = t >> 2, q = t & 3;
        const float4* p = (const float4*)(s1 + (size_t)(ty1 * 16 + r) * 256 + tx1 * 16);
        ((float4*)&stL1[r * 20])[q] = p[q];
    }

    float oy, ox, od;
    {
        float dyf, dxf; inherit_off(ty1, tx1, 256, poy, pox, dyf, dxf);
        load_win<256>(d1, 256, ty1 * 16 + (int)dyf - 5, tx1 * 16 + (int)dxf - 5, win_c, t);
        __syncthreads();
        ssd_dist<true>(win_c, stL1, dist_c, t);
        __syncthreads();
        argmin_refine(dist_c, t, dyf, dxf, oy, ox, od);
    }
    if (t == 0) {
        const int o1 = (((b * 16) + ty1) * 16 + tx1) * 2;
        offs1[o1]     = oy;
        offs1[o1 + 1] = ox;
    }
}

// ---------------------------------------------------------------------------
// K2b2: S0-only. One block per S0 tile (4096 blocks, 128 thr = 2 waves,
// LB(128,4): 64-VGPR no-spill config). Loads parent S1 offset; one verbatim
// 2-row/8-lane SSD round; argmin + fused pixel expand.
// LDS: win 728 | dist 128 | st 320 = 1176 fl = 4.7 KB.
// ---------------------------------------------------------------------------
__global__ void __launch_bounds__(128, 4)
s0_kernel(const float* __restrict__ src, const float* __restrict__ dst,
          const float* __restrict__ ws, float* __restrict__ out) {
    __shared__ float smem[1176];
    float* win  = smem;
    float* dist = smem + 728;
    float* st   = smem + 856;       // [16][20]

    const float* offs1 = ws + OFFS1_BASE;

    const int gid = blockIdx.x;
    const int b   = gid >> 10;
    const int ty0 = (gid >> 5) & 31;
    const int tx0 = gid & 31;
    const int t   = threadIdx.x;    // 0..127

    const float* s0 = src + (size_t)b * 262144;
    const float* d0 = dst + (size_t)b * 262144;

    // Parent S1 offset (uniform per block).
    const int o1 = (((b * 16) + (ty0 >> 1)) * 16 + (tx0 >> 1)) * 2;
    const float poy = offs1[o1], pox = offs1[o1 + 1];

    // Entry: st load (stride-20 rows; 64 lanes).
    if (t < 64) {
        const int r = t >> 2, q = t & 3;
        const float4* p = (const float4*)(s0 + (size_t)(ty0 * 16 + r) * 512 + tx0 * 16);
        ((float4*)&st[r * 20])[q] = p[q];
    }

    float dyf, dxf;
    inherit_off(ty0, tx0, 512, poy, pox, dyf, dxf);
    load_win<128>(d0, 512, ty0 * 16 + (int)dyf - 5, tx0 * 16 + (int)dxf - 5, win, t);
    __syncthreads();
    ssd_dist<false>(win, st, dist, t);
    __syncthreads();

    float oy, ox, od;
    argmin_refine(dist, t, dyf, dxf, oy, ox, od);

    // Fused expand: 256 px per tile, 2 px/lane (float2 writes).
    const int r = t >> 3, c2 = (t & 7) * 2;
    int pyy = ty0 * 16 + r, pxx = tx0 * 16 + c2;
    size_t pi = ((size_t)(b * 512 + pyy)) * 512 + pxx;
    float2 o; o.x = oy; o.y = ox;
    ((float2*)out)[pi]     = o;
    ((float2*)out)[pi + 1] = o;
    float2 dd; dd.x = od; dd.y = od;
    *(float2*)(out + (size_t)NPIX * 2 + pi) = dd;
}

extern "C" void kernel_launch(void* const* d_in, const int* in_sizes, int n_in,
                              void* d_out, int out_size, void* d_ws, size_t ws_size,
                              hipStream_t stream) {
    const float* src = (const float*)d_in[0];   // (4,1,512,512)
    const float* dst = (const float*)d_in[1];   // (4,1,512,512)
    float* out = (float*)d_out;                  // offsets (NPIX*2) ++ dist (NPIX)
    float* ws  = (float*)d_ws;                   // pyramid levels + seed offsets

    hipLaunchKernelGGL(pyramid_kernel, dim3(8, 16, 8), dim3(256), 0, stream, src, dst, ws);
    hipLaunchKernelGGL(seed_kernel, dim3(256), dim3(256), 0, stream, (const float*)ws, ws);
    hipLaunchKernelGGL(s1_kernel, dim3(1024), dim3(256), 0, stream, (const float*)ws, ws);
    hipLaunchKernelGGL(s0_kernel, dim3(4096), dim3(128), 0, stream, src, dst, (const float*)ws, out);
}

// Round 18
// 102.308 us; speedup vs baseline: 1.0494x; 1.0494x over previous
//
#include <hip/hip_runtime.h>

// HDR+ align, 3-kernel version, round 21 = exact revert to R19 (best,
// 102.75us). R20's 4-kernel split regressed (-6us: extra launch boundary
// cost more than the S0 phase's occupancy gain). Structure: K1 pyramid
// (8x4-tile blocks), K2a seed (S3->S2 once per S2 tile), K2b chain (S1 +
// dual-S0, fused expand). All SSD/argmin internals are the proven bitwise
// paths; st rows stride-20 (bank-conflict pad), division-free window loads.
// Constants: T=16, SR=4, PADD=1, SS=11, SSC=9, WIN=26, SW=0.1, GR=2, batch 4, 512x512.

#define NB 4
#define NPIX (NB * 512 * 512)
#define OFFS_BASE 1212416   // floats: after dL3 (4.85 MB); 512 floats used

// Composite 1D tap of (normalized gaussian sigma=1 r=2) followed by avg-pool-2.
constexpr float H6[6] = {
    0.027244342f, 0.149345013f, 0.323410645f,
    0.323410645f, 0.149345013f, 0.027244342f
};

// ---------------------------------------------------------------------------
// K1: pyramid. One block = 8x4 region of L3 (covers 64x32 L0). Grid (8,16,8).
// ---------------------------------------------------------------------------
__global__ void __launch_bounds__(256, 4)
pyramid_kernel(const float* __restrict__ src, const float* __restrict__ dst,
               float* __restrict__ ws) {
    __shared__ float smem[8160];
    float* patch = smem;            // 60 rows, stride 92
    float* tmpH1 = smem + 5520;     // 60 rows, stride 44
    float* l1    = smem;            // 28 rows, stride 44
    float* tmpH2 = smem + 1232;     // 28 rows, stride 20
    float* l2    = smem + 1792;     // 12 rows, stride 20
    float* tmpH3 = smem + 2032;     // 12 rows, stride 8

    float* sL1 = ws;
    float* dL1 = sL1 + 4 * 65536;
    float* sL2 = dL1 + 4 * 65536;
    float* dL2 = sL2 + 4 * 16384;
    float* sL3 = dL2 + 4 * 16384;
    float* dL3 = sL3 + 4 * 4096;

    const int bx = blockIdx.x, by = blockIdx.y, z = blockIdx.z;
    const int t = threadIdx.x;
    const float* in = (z < 4) ? (src + (size_t)z * 262144) : (dst + (size_t)(z - 4) * 262144);
    float* oL1 = ((z < 4) ? sL1 : dL1) + (size_t)(z & 3) * 65536;
    float* oL2 = ((z < 4) ? sL2 : dL2) + (size_t)(z & 3) * 16384;
    float* oL3 = ((z < 4) ? sL3 : dL3) + (size_t)(z & 3) * 4096;

    // P0: 60x92 L0 patch at (by*32-14, bx*64-14), zero OOB (conv zero-pad).
    {
        const int oy = by * 32 - 14, ox = bx * 64 - 14;
        for (int idx = t; idx < 5520; idx += 256) {
            int r = idx / 92, c = idx - r * 92;
            int gy = oy + r, gx = ox + c;
            float v = 0.f;
            if ((unsigned)gy < 512u && (unsigned)gx < 512u) v = in[gy * 512 + gx];
            patch[r * 92 + c] = v;
        }
    }
    __syncthreads();
    // P1: horizontal -> tmpH1[60][44]
    for (int idx = t; idx < 2640; idx += 256) {
        int r = idx / 44, v = idx - r * 44;
        const float* p = &patch[r * 92 + 2 * v];
        float a = 0.f;
        #pragma unroll
        for (int bq = 0; bq < 6; ++bq) a = fmaf(H6[bq], p[bq], a);
        tmpH1[r * 44 + v] = a;
    }
    __syncthreads();
    // P2: vertical -> l1[28][44]; zero if L1 coord OOB (per-level zero-pad).
    {
        const int oy = by * 16 - 6, ox = bx * 32 - 6;
        for (int idx = t; idx < 1232; idx += 256) {
            int u = idx / 44, v = idx - u * 44;
            float a = 0.f;
            int y1 = oy + u, x1 = ox + v;
            if ((unsigned)y1 < 256u && (unsigned)x1 < 256u) {
                #pragma unroll
                for (int bq = 0; bq < 6; ++bq) a = fmaf(H6[bq], tmpH1[(2 * u + bq) * 44 + v], a);
            }
            l1[u * 44 + v] = a;
        }
    }
    __syncthreads();
    // P3: write canonical L1 16x32 + horizontal -> tmpH2[28][20]
    {
        #pragma unroll
        for (int k = 0; k < 2; ++k) {
            int idx = t + k * 256;
            int u = idx >> 5, v = idx & 31;
            oL1[(by * 16 + u) * 256 + bx * 32 + v] = l1[(6 + u) * 44 + 6 + v];
        }
    }
    for (int idx = t; idx < 560; idx += 256) {
        int r = idx / 20, v = idx - r * 20;
        const float* p = &l1[r * 44 + 2 * v];
        float a = 0.f;
        #pragma unroll
        for (int bq = 0; bq < 6; ++bq) a = fmaf(H6[bq], p[bq], a);
        tmpH2[r * 20 + v] = a;
    }
    __syncthreads();
    // P4: vertical -> l2[12][20]; zero if L2 coord OOB.
    {
        const int oy = by * 8 - 2, ox = bx * 16 - 2;
        if (t < 240) {
            int u = t / 20, v = t - u * 20;
            float a = 0.f;
            int y2 = oy + u, x2 = ox + v;
            if ((unsigned)y2 < 128u && (unsigned)x2 < 128u) {
                #pragma unroll
                for (int bq = 0; bq < 6; ++bq) a = fmaf(H6[bq], tmpH2[(2 * u + bq) * 20 + v], a);
            }
            l2[u * 20 + v] = a;
        }
    }
    __syncthreads();
    // P5: write canonical L2 8x16 + horizontal -> tmpH3[12][8]
    if (t < 128) {
        int u = t >> 4, v = t & 15;
        oL2[(by * 8 + u) * 128 + bx * 16 + v] = l2[(2 + u) * 20 + 2 + v];
    } else if (t < 224) {
        int idx = t - 128;
        int r = idx >> 3, v = idx & 7;
        const float* p = &l2[r * 20 + 2 * v];
        float a = 0.f;
        #pragma unroll
        for (int bq = 0; bq < 6; ++bq) a = fmaf(H6[bq], p[bq], a);
        tmpH3[r * 8 + v] = a;
    }
    __syncthreads();
    // P6: vertical -> L3 4x8, write global.
    if (t < 32) {
        int u = t >> 3, v = t & 7;
        float a = 0.f;
        #pragma unroll
        for (int bq = 0; bq < 6; ++bq) a = fmaf(H6[bq], tmpH3[(2 * u + bq) * 8 + v], a);
        oL3[(by * 4 + u) * 64 + bx * 8 + v] = a;
    }
}

// ---------------------------------------------------------------------------
// K2 helpers (SSD/argmin bit-identical to the proven paths; st row stride 20).
// ---------------------------------------------------------------------------
__device__ __forceinline__ void inherit_off(int ty, int tx, int H,
                                            float pary, float parx,
                                            float& dyf, float& dxf) {
    float iy = (float)(ty * 16), ix = (float)(tx * 16);
    // _inherit: round(clip(2*par + i, 0, H-16) - i), half-to-even (rintf).
    dyf = rintf(fminf(fmaxf(2.f * pary + iy, 0.f), (float)(H - 16)) - iy);
    dxf = rintf(fminf(fmaxf(2.f * parx + ix, 0.f), (float)(H - 16)) - ix);
}

// Division-free window load: lane owns column c = lt&31 (clamp hoisted),
// rows stride by NL/32.
template<int NL>
__device__ __forceinline__ void load_win(const float* __restrict__ dimg, int H,
                                         int y0, int x0, float* win, int lt) {
    const int c = lt & 31;
    const int r0 = lt >> 5;              // NL=256: 0..7 ; NL=128: 0..3
    constexpr int RSTEP = NL / 32;
    if (c < 26) {
        const int gx = min(max(x0 + c, 0), H - 1);
        #pragma unroll
        for (int k = 0; k < (26 + RSTEP - 1) / RSTEP; ++k) {
            const int rr = r0 + k * RSTEP;
            if (rr < 26) {
                const int gy = min(max(y0 + rr, 0), H - 1);
                win[rr * 28 + c] = dimg[gy * H + gx];
            }
        }
    }
}

// SSD + dist write. FULL: 1 row/lane, 16-lane dy-groups (lt in [0,256)).
// !FULL: 2 rows/lane, 8-lane dy-groups (lt in [0,128)). No barriers inside.
template<bool FULL>
__device__ __forceinline__ void ssd_dist(const float* win, const float* st,
                                         float* dist, int lt) {
    const int dy = FULL ? (lt >> 4) : (lt >> 3);
    if (dy < 11) {
        float acc[11];
        #pragma unroll
        for (int q = 0; q < 11; ++q) acc[q] = 0.f;
        constexpr int ROWS = FULL ? 1 : 2;
        #pragma unroll
        for (int rr = 0; rr < ROWS; ++rr) {
            const int i = FULL ? (lt & 15) : ((lt & 7) * 2 + rr);
            float w[28], s[16];
            const float4* wp = (const float4*)&win[(dy + i) * 28];
            #pragma unroll
            for (int q = 0; q < 7; ++q) ((float4*)w)[q] = wp[q];
            const float4* sp = (const float4*)&st[i * 20];
            #pragma unroll
            for (int q = 0; q < 4; ++q) ((float4*)s)[q] = sp[q];
            #pragma unroll
            for (int dx = 0; dx < 11; ++dx) {
                #pragma unroll
                for (int j = 0; j < 16; ++j) {
                    float d = w[dx + j] - s[j];
                    acc[dx] = fmaf(d, d, acc[dx]);
                }
            }
        }
        constexpr int MMAX = FULL ? 8 : 4;
        #pragma unroll
        for (int m = 1; m <= MMAX; m <<= 1) {
            #pragma unroll
            for (int dx = 0; dx < 11; ++dx) acc[dx] += __shfl_xor(acc[dx], m);
        }
        const bool leader = FULL ? ((lt & 15) == 0) : ((lt & 7) == 0);
        if (leader) {
            float ay = (float)(dy - 5) * (1.f / 11.f);
            #pragma unroll
            for (int dx = 0; dx < 11; ++dx) {
                float ax = (float)(dx - 5) * (1.f / 11.f);
                dist[dy * 11 + dx] = acc[dx] * (1.f / 256.f) + 0.1f * (ay * ay + ax * ax);
            }
        }
    }
}

// Redundant per-lane argmin over central 9x9 + subpixel refine (baseline).
__device__ __forceinline__ void argmin_refine(const float* dist, int lt,
                                              float dyf, float dxf,
                                              float& roy, float& rox, float& rod) {
    const int l = lt & 63;
    float bv; int bk;
    {
        int k = l;                                    // 0..63 < 81 always
        int py = k / 9, px = k - (k / 9) * 9;
        bv = dist[(py + 1) * 11 + (px + 1)]; bk = k;
        k = l + 64;
        if (k < 81) {
            py = k / 9; px = k - (k / 9) * 9;
            float d = dist[(py + 1) * 11 + (px + 1)];
            if (d < bv) { bv = d; bk = k; }           // strict: tie keeps smaller k
        }
    }
    #pragma unroll
    for (int m = 1; m <= 32; m <<= 1) {
        float ov = __shfl_xor(bv, m);
        int   ok = __shfl_xor(bk, m);
        if (ov < bv || (ov == bv && ok < bk)) { bv = ov; bk = ok; }
    }
    {
        int py = bk / 9, px = bk - (bk / 9) * 9;
        float y00 = dist[(py + 0) * 11 + (px + 0)], y01 = dist[(py + 0) * 11 + (px + 1)], y02 = dist[(py + 0) * 11 + (px + 2)];
        float y10 = dist[(py + 1) * 11 + (px + 0)], y11 = dist[(py + 1) * 11 + (px + 1)], y12 = dist[(py + 1) * 11 + (px + 2)];
        float y20 = dist[(py + 2) * 11 + (px + 0)], y21 = dist[(py + 2) * 11 + (px + 1)], y22 = dist[(py + 2) * 11 + (px + 2)];

        float a11 = (y00 - 2.f * y01 + y02 + 2.f * y10 - 4.f * y11 + 2.f * y12 + y20 - 2.f * y21 + y22) * 0.25f;
        a11 = fmaxf(a11, 0.f);
        float a22 = (y00 + 2.f * y01 + y02 - 2.f * y10 - 4.f * y11 - 2.f * y12 + y20 + 2.f * y21 + y22) * 0.25f;
        a22 = fmaxf(a22, 0.f);
        float a12 = (y00 - y02 - y20 + y22) * 0.25f;
        float b1  = (-y00 + y02 - 2.f * y10 + 2.f * y12 - y20 + y22) * 0.125f;
        float b2  = (-y00 - 2.f * y01 - y02 + y20 + 2.f * y21 + y22) * 0.125f;

        float det  = a11 * a22 - a12 * a12;
        float a12z = (det < 0.f) ? 0.f : a12;
        float mu_x = -(a22 * b1 - a12z * b2) / det;   // inf/nan when det==0 -> filtered
        float mu_y = -(a11 * b2 - a12z * b1) / det;
        float mu_len = sqrtf(mu_x * mu_x + mu_y * mu_y);
        float addx = (mu_len < 1.f) ? mu_x : 0.f;     // NaN -> false, matches jnp.where
        float addy = (mu_len < 1.f) ? mu_y : 0.f;

        roy = dyf + (float)(py - 4) + addy;
        rox = dxf + (float)(px - 4) + addx;
        rod = bv;
    }
}

// ---------------------------------------------------------------------------
// K2a: seed kernel. One block per S2 tile (256 blocks, 256 thr, 1 block/CU).
// Computes S3 (parent, redundant x4 siblings -- bitwise identical) then S2,
// writes the final S2 offset (2 floats) to ws offs.
// ---------------------------------------------------------------------------
__global__ void __launch_bounds__(256, 4)
seed_kernel(const float* __restrict__ ws_ro, float* __restrict__ ws) {
    __shared__ float smem[1496];
    float* win_c  = smem;
    float* dist_c = smem + 728;
    float* stL3   = smem + 856;     // [16][20]
    float* stL2   = smem + 1176;    // [16][20]

    const float* sL2 = ws_ro + 4 * 65536 + 4 * 65536;
    const float* dL2 = sL2 + 4 * 16384;
    const float* sL3 = dL2 + 4 * 16384;
    const float* dL3 = sL3 + 4 * 4096;
    float* offs = ws + OFFS_BASE;

    const int gid = blockIdx.x;
    const int b   = gid >> 6;
    const int ty2 = (gid >> 3) & 7;
    const int tx2 = gid & 7;
    const int t   = threadIdx.x;

    const float* s2 = sL2 + (size_t)b * 16384;  const float* d2 = dL2 + (size_t)b * 16384;
    const float* s3 = sL3 + (size_t)b * 4096;   const float* d3 = dL3 + (size_t)b * 4096;

    // Entry: st loads (stride-20 rows).
    {
        const int it = t & 63, r = it >> 2, q = t & 3;
        if (t < 64) {
            const float4* p = (const float4*)(s3 + (size_t)((ty2 >> 1) * 16 + r) * 64 + (tx2 >> 1) * 16);
            ((float4*)&stL3[r * 20])[q] = p[q];
        } else if (t < 128) {
            const float4* p = (const float4*)(s2 + (size_t)(ty2 * 16 + r) * 128 + tx2 * 16);
            ((float4*)&stL2[r * 20])[q] = p[q];
        }
    }

    float oy, ox, od;
    // S3 (init offset 0)
    load_win<256>(d3, 64, (ty2 >> 1) * 16 - 5, (tx2 >> 1) * 16 - 5, win_c, t);
    __syncthreads();
    ssd_dist<true>(win_c, stL3, dist_c, t);
    __syncthreads();
    argmin_refine(dist_c, t, 0.f, 0.f, oy, ox, od);
    // S2
    {
        float dyf, dxf; inherit_off(ty2, tx2, 128, oy, ox, dyf, dxf);
        load_win<256>(d2, 128, ty2 * 16 + (int)dyf - 5, tx2 * 16 + (int)dxf - 5, win_c, t);
        __syncthreads();
        ssd_dist<true>(win_c, stL2, dist_c, t);
        __syncthreads();
        argmin_refine(dist_c, t, dyf, dxf, oy, ox, od);
    }
    if (t == 0) {
        const int oi = ((b * 8 + ty2) * 8 + tx2) * 2;
        offs[oi]     = oy;
        offs[oi + 1] = ox;
    }
}

// ---------------------------------------------------------------------------
// K2b: one block per S1 tile (1024 blocks, 256 thr, 4 blocks/CU). Loads the
// parent S2 offset from ws (stream-ordered after K2a); runs S1 then S0 (both
// halves per 128-slot, merged window loads, SSD-A -> bar -> SSD-B).
// ---------------------------------------------------------------------------
__global__ void __launch_bounds__(256, 4)
step_chain_kernel(const float* __restrict__ src, const float* __restrict__ dst,
                  const float* __restrict__ ws, float* __restrict__ out) {
    __shared__ float smem[5880];

    const float* sL1 = ws;
    const float* offs = ws + OFFS_BASE;

    const int gid = blockIdx.x;
    const int b   = gid >> 8;
    const int ty1 = (gid >> 4) & 15;
    const int tx1 = gid & 15;
    const int t    = threadIdx.x;
    const int slot = t >> 7;        // 0..1
    const int s_t  = t & 127;

    float* win_c  = smem;
    float* winA   = smem + 728 + (2 * slot + 0) * 728;
    float* winB   = smem + 728 + (2 * slot + 1) * 728;
    float* dist_c = smem + 3640;
    float* distA  = smem + 3768 + (2 * slot + 0) * 128;
    float* distB  = smem + 3768 + (2 * slot + 1) * 128;
    float* stL1 = smem + 4280;      // [16][20]
    float* st0  = smem + 4600;      // [4][16][20], child c = 2*half + slot

    const float* s0 = src + (size_t)b * 262144; const float* d0 = dst + (size_t)b * 262144;
    const float* s1 = sL1 + (size_t)b * 65536;
    const float* d1 = sL1 + 4 * 65536 + (size_t)b * 65536;

    // Parent S2 offset (uniform per block; broadcast load).
    const int oi = ((b * 8 + (ty1 >> 1)) * 8 + (tx1 >> 1)) * 2;
    const float poy = offs[oi], pox = offs[oi + 1];

    // ---- Entry: st loads (stride-20 rows) ----
    {
        const int it = t & 63, r = it >> 2, q = t & 3;
        // S0: 4 children x 64 float4 items = exactly 256 threads.
        const int c = t >> 6;
        const int ty0 = 2 * ty1 + (c >> 1), tx0 = 2 * tx1 + (c & 1);
        const float4* p0 = (const float4*)(s0 + (size_t)(ty0 * 16 + r) * 512 + tx0 * 16);
        ((float4*)&st0[c * 320 + r * 20])[q] = p0[q];
        if (t < 64) {
            const float4* p = (const float4*)(s1 + (size_t)(ty1 * 16 + r) * 256 + tx1 * 16);
            ((float4*)&stL1[r * 20])[q] = p[q];
        }
    }

    float oy, ox, od;
    // ---- S1 ----
    {
        float dyf, dxf; inherit_off(ty1, tx1, 256, poy, pox, dyf, dxf);
        load_win<256>(d1, 256, ty1 * 16 + (int)dyf - 5, tx1 * 16 + (int)dxf - 5, win_c, t);
        __syncthreads();
        ssd_dist<true>(win_c, stL1, dist_c, t);
        __syncthreads();
        argmin_refine(dist_c, t, dyf, dxf, oy, ox, od);
    }

    // ---- S0: both halves per slot, windows loaded together ----
    const int tyA = 2 * ty1,     txA = 2 * tx1 + slot;   // half 0
    const int tyB = 2 * ty1 + 1, txB = 2 * tx1 + slot;   // half 1
    float dyfA, dxfA, dyfB, dxfB;
    inherit_off(tyA, txA, 512, oy, ox, dyfA, dxfA);
    inherit_off(tyB, txB, 512, oy, ox, dyfB, dxfB);
    load_win<128>(d0, 512, tyA * 16 + (int)dyfA - 5, txA * 16 + (int)dxfA - 5, winA, s_t);
    load_win<128>(d0, 512, tyB * 16 + (int)dyfB - 5, txB * 16 + (int)dxfB - 5, winB, s_t);
    __syncthreads();
    ssd_dist<false>(winA, st0 + (0 * 2 + slot) * 320, distA, s_t);
    __syncthreads();   // bounds register peak to single-SSD shape (anti-spill)
    ssd_dist<false>(winB, st0 + (1 * 2 + slot) * 320, distB, s_t);
    __syncthreads();

    // ---- argmin + fused pixel expand (2 px/lane per half, float2 writes) ----
    const int r = s_t >> 3, c2 = (s_t & 7) * 2;
    {
        float oyA, oxA, odA;
        argmin_refine(distA, s_t, dyfA, dxfA, oyA, oxA, odA);
        int pyy = tyA * 16 + r, pxx = txA * 16 + c2;
        size_t pi = ((size_t)(b * 512 + pyy)) * 512 + pxx;
        float2 o; o.x = oyA; o.y = oxA;
        ((float2*)out)[pi]     = o;
        ((float2*)out)[pi + 1] = o;
        float2 dd; dd.x = odA; dd.y = odA;
        *(float2*)(out + (size_t)NPIX * 2 + pi) = dd;
    }
    {
        float oyB, oxB, odB;
        argmin_refine(distB, s_t, dyfB, dxfB, oyB, oxB, odB);
        int pyy = tyB * 16 + r, pxx = txB * 16 + c2;
        size_t pi = ((size_t)(b * 512 + pyy)) * 512 + pxx;
        float2 o; o.x = oyB; o.y = oxB;
        ((float2*)out)[pi]     = o;
        ((float2*)out)[pi + 1] = o;
        float2 dd; dd.x = odB; dd.y = odB;
        *(float2*)(out + (size_t)NPIX * 2 + pi) = dd;
    }
}

extern "C" void kernel_launch(void* const* d_in, const int* in_sizes, int n_in,
                              void* d_out, int out_size, void* d_ws, size_t ws_size,
                              hipStream_t stream) {
    const float* src = (const float*)d_in[0];   // (4,1,512,512)
    const float* dst = (const float*)d_in[1];   // (4,1,512,512)
    float* out = (float*)d_out;                  // offsets (NPIX*2) ++ dist (NPIX)
    float* ws  = (float*)d_ws;                   // pyramid levels + seed offsets

    hipLaunchKernelGGL(pyramid_kernel, dim3(8, 16, 8), dim3(256), 0, stream, src, dst, ws);
    hipLaunchKernelGGL(seed_kernel, dim3(256), dim3(256), 0, stream, (const float*)ws, ws);
    hipLaunchKernelGGL(step_chain_kernel, dim3(1024), dim3(256), 0, stream, src, dst, ws, out);
}